// Round 3
// baseline (1040.848 us; speedup 1.0000x reference)
//
#include <hip/hip_runtime.h>
#include <cfloat>
#include <climits>

#define NPTS 8192
#define NDIM 64
#define NB   2
#define KK   16

// ---------- numpy f32 sum model: AVX512 pairwise(64) + reduce_add tree ----
__device__ __forceinline__ float np_sum64(const float* v) {
#pragma clang fp contract(off)
    float L[16], M[8], P[4];
#pragma unroll
    for (int l = 0; l < 16; ++l)
        L[l] = __fadd_rn(__fadd_rn(v[l], v[16 + l]), __fadd_rn(v[32 + l], v[48 + l]));
#pragma unroll
    for (int l = 0; l < 8; ++l) M[l] = __fadd_rn(L[l], L[l + 8]);
#pragma unroll
    for (int l = 0; l < 4; ++l) P[l] = __fadd_rn(M[l], M[l + 4]);
    return __fadd_rn(__fadd_rn(P[0], P[2]), __fadd_rn(P[1], P[3]));
}

// ---------- prep: s[] via np model; xT[n][c] contiguous transpose ----------
__global__ __launch_bounds__(256) void k_prep(const float* __restrict__ x,
                                              float* __restrict__ s,
                                              float* __restrict__ xT) {
#pragma clang fp contract(off)
    int g = blockIdx.x * 256 + threadIdx.x;       // 0 .. NB*NPTS-1
    int b = g / NPTS, n = g % NPTS;
    const float* xb = x + (size_t)b * NDIM * NPTS + n;
    float a[NDIM], v[NDIM];
#pragma unroll
    for (int c = 0; c < NDIM; ++c) {
        a[c] = xb[(size_t)c * NPTS];
        v[c] = __fmul_rn(a[c], a[c]);
    }
    s[g] = np_sum64(v);
    float4* dst = (float4*)(xT + (size_t)g * NDIM);
#pragma unroll
    for (int q = 0; q < NDIM / 4; ++q)
        dst[q] = make_float4(a[4 * q], a[4 * q + 1], a[4 * q + 2], a[4 * q + 3]);
}

// ---------- main: thread-per-row, per-chunk top-16 by np-model f32 d -------
__global__ __launch_bounds__(256) void k_main(const float* __restrict__ x,
                                              const float* __restrict__ xT,
                                              const float* __restrict__ s,
                                              float* __restrict__ wd,
                                              int* __restrict__ wi,
                                              int js, int jlen) {
#pragma clang fp contract(off)
    const int tid   = threadIdx.x;
    const int bi    = blockIdx.x & 63;   // b*32 + itile
    const int chunk = blockIdx.x >> 6;
    const int b     = bi >> 5;
    const int itile = bi & 31;
    const int i     = itile * 256 + tid;
    const int boff  = b * NPTS;

    // own row coords (coalesced strided loads from original layout)
    const float* xb = x + (size_t)b * NDIM * NPTS + i;
    float a[NDIM];
#pragma unroll
    for (int c = 0; c < NDIM; ++c) a[c] = xb[(size_t)c * NPTS];
    const float si = s[boff + i];

    float ld[KK]; int li[KK];
#pragma unroll
    for (int e = 0; e < KK; ++e) { ld[e] = FLT_MAX; li[e] = INT_MAX; }
    float ldL = FLT_MAX;

    const int j0 = chunk * jlen;
    for (int j = j0; j < j0 + jlen; j += 4) {
        const float* bp = xT + ((size_t)boff + j) * NDIM;   // wave-uniform
        float acc0 = 0.f, acc1 = 0.f, acc2 = 0.f, acc3 = 0.f;
#pragma unroll
        for (int c = 0; c < NDIM; ++c) {
            float av = a[c];
            acc0 = __fadd_rn(acc0, __fmul_rn(av, bp[c]));
            acc1 = __fadd_rn(acc1, __fmul_rn(av, bp[NDIM + c]));
            acc2 = __fadd_rn(acc2, __fmul_rn(av, bp[2 * NDIM + c]));
            acc3 = __fadd_rn(acc3, __fmul_rn(av, bp[3 * NDIM + c]));
        }
        float dq[4];
        dq[0] = __fadd_rn(__fadd_rn(si, __fmul_rn(-2.0f, acc0)), s[boff + j + 0]);
        dq[1] = __fadd_rn(__fadd_rn(si, __fmul_rn(-2.0f, acc1)), s[boff + j + 1]);
        dq[2] = __fadd_rn(__fadd_rn(si, __fmul_rn(-2.0f, acc2)), s[boff + j + 2]);
        dq[3] = __fadd_rn(__fadd_rn(si, __fmul_rn(-2.0f, acc3)), s[boff + j + 3]);
#pragma unroll
        for (int q = 0; q < 4; ++q) {
            float d = dq[q];
            if (d < ldL) {                 // ascending-j scan + strict < = stable
                float cd = d; int ci = j + q;
#pragma unroll
                for (int e = 0; e < KK; ++e) {
                    bool sw = cd < ld[e];
                    float od = ld[e]; int oi = li[e];
                    ld[e] = sw ? cd : od;  li[e] = sw ? ci : oi;
                    cd    = sw ? od : cd;  ci    = sw ? oi : ci;
                }
                ldL = ld[KK - 1];
            }
        }
    }

    const size_t base = ((size_t)(boff + i) * js + chunk) * KK;
#pragma unroll
    for (int e = 0; e < KK; ++e) { wd[base + e] = ld[e]; wi[base + e] = li[e]; }
}

// ---------- merge chunks by (d, idx) lex, write outputs --------------------
__global__ __launch_bounds__(256) void k_merge(const float* __restrict__ wd,
                                               const int* __restrict__ wi,
                                               int* __restrict__ out,
                                               int js) {
    int g = blockIdx.x * 256 + threadIdx.x;   // 0 .. NB*NPTS-1
    int i = g % NPTS;

    float md[KK]; int mi[KK];
#pragma unroll
    for (int e = 0; e < KK; ++e) { md[e] = FLT_MAX; mi[e] = INT_MAX; }

    const size_t base = (size_t)g * js * KK;
    const int tot = js * KK;
    for (int t = 0; t < tot; ++t) {
        float d = wd[base + t];
        int  ix = wi[base + t];
        bool better = (d < md[KK - 1]) || (d == md[KK - 1] && ix < mi[KK - 1]);
        if (better) {
            float cd = d; int ci = ix;
#pragma unroll
            for (int e = 0; e < KK; ++e) {
                bool sw = (cd < md[e]) || (cd == md[e] && ci < mi[e]);
                float od = md[e]; int oi = mi[e];
                md[e] = sw ? cd : od;  mi[e] = sw ? ci : oi;
                cd    = sw ? od : cd;  ci    = sw ? oi : ci;
            }
        }
    }

    const size_t ob = (size_t)g * KK;
#pragma unroll
    for (int e = 0; e < KK; ++e) {
        out[ob + e] = mi[e];                                  // nn_idx
        out[(size_t)NB * NPTS * KK + ob + e] = i;             // center_idx
    }
}

extern "C" void kernel_launch(void* const* d_in, const int* in_sizes, int n_in,
                              void* d_out, int out_size, void* d_ws, size_t ws_size,
                              hipStream_t stream) {
    const float* x = (const float*)d_in[0];
    int* out = (int*)d_out;

    const size_t S_BYTES  = 65536;                 // s: 16384 f32 (64KB)
    const size_t XT_BYTES = (size_t)NB * NPTS * NDIM * 4;   // 4MB

    int js = 16;
    while (js > 1) {
        size_t need = S_BYTES + XT_BYTES + (size_t)NB * NPTS * js * KK * 8;
        if (need <= ws_size) break;
        js >>= 1;
    }
    float* s  = (float*)d_ws;
    float* xT = (float*)((char*)d_ws + S_BYTES);
    float* wd = (float*)((char*)d_ws + S_BYTES + XT_BYTES);
    int*   wi = (int*)((char*)d_ws + S_BYTES + XT_BYTES + (size_t)NB * NPTS * js * KK * 4);
    const int jlen = NPTS / js;

    k_prep <<<NB * NPTS / 256, 256, 0, stream>>>(x, s, xT);
    k_main <<<NB * (NPTS / 256) * js, 256, 0, stream>>>(x, xT, s, wd, wi, js, jlen);
    k_merge<<<NB * NPTS / 256, 256, 0, stream>>>(wd, wi, out, js);
}